// Round 3
// baseline (3542.918 us; speedup 1.0000x reference)
//
#include <hip/hip_runtime.h>

// GraphProp: N nodes, E edges, H=128, T rounds.
// Identity 1 (linearity of segment_sum over the edge GEMM):
//   a[v] = deg(v)*(Wd@hv[v] + bmsg) + Ws@s[v] + g[v]*we
//   with s[v]=sum hv[src_e], g[v]=sum he_e over incoming edges of v.
// Identity 2 (per-row scalar deg commutes with the GRU input GEMM):
//   gi = Wih@a + bih = A1@(deg*hv) + A2@s + deg*c1 + g*c2 + bih
//   where A1=Wih@Wd, A2=Wih@Ws, c1=Wih@bmsg, c2=Wih@we.
// So one GEMM per round: G[v] = Wbig @ x[v], x=[deg*hv | s | hv] (384),
//   Wbig rows 0:256  = [A1_rz | A2_rz | Whh_rz]   (r,z: gi+gh combined)
//   Wbig rows 256:384= [A1_n  | A2_n  | 0     ]   (i_n)
//   Wbig rows 384:512= [0     | 0     | Whh_n ]   (h_n)
// No [E,256] activation and no [N,256] 'a' are ever materialized.

#define BM 64
#define BN 64
#define BK 16
#define LDSD 68   // 68 floats = 272B stride, 16B-aligned for b128 LDS reads

__global__ void build_wbig_kernel(const float* __restrict__ Wih,
                                  const float* __restrict__ Whh,
                                  const float* __restrict__ Wmsg,
                                  const float* __restrict__ bmsg,
                                  float* __restrict__ Wbig,
                                  float* __restrict__ cvec) {
  int c = blockIdx.x * blockDim.x + threadIdx.x;  // 0..385 (384=c1, 385=c2)
  int o = blockIdx.y;                             // 0..511
  int t = blockIdx.z;
  if (c >= 386) return;
  const float* wih  = Wih  + (size_t)t * 384 * 256;
  const float* whh  = Whh  + (size_t)t * 384 * 128;
  const float* wmsg = Wmsg + (size_t)t * 256 * 257;
  const float* bm   = bmsg + (size_t)t * 256;
  float* wb = Wbig + (size_t)t * 512 * 384;
  float* cv = cvec + (size_t)t * 768;
  if (c < 384) {
    float val = 0.0f;
    if (c < 256) {
      if (o < 384) {                 // A1|A2 = Wih @ Wmsg[:, 0:256]
        float acc = 0.0f;
        for (int k = 0; k < 256; ++k) acc += wih[(size_t)o * 256 + k] * wmsg[(size_t)k * 257 + c];
        val = acc;
      }
    } else {
      if (o < 256)       val = whh[(size_t)o * 128 + (c - 256)];
      else if (o >= 384) val = whh[(size_t)(256 + o - 384) * 128 + (c - 256)];
    }
    wb[(size_t)o * 384 + c] = val;
  } else if (o < 384) {
    float acc = 0.0f;
    if (c == 384) {
      for (int k = 0; k < 256; ++k) acc += wih[(size_t)o * 256 + k] * bm[k];
      cv[o] = acc;                   // c1
    } else {
      for (int k = 0; k < 256; ++k) acc += wih[(size_t)o * 256 + k] * wmsg[(size_t)k * 257 + 256];
      cv[384 + o] = acc;             // c2
    }
  }
}

__global__ void edge_scatter_kernel(const float* __restrict__ hv,
                                    const float* __restrict__ he,
                                    const int* __restrict__ src,
                                    const int* __restrict__ dst,
                                    float* __restrict__ s,
                                    float* __restrict__ g,
                                    float* __restrict__ deg,
                                    int E) {
  int gid = blockIdx.x * blockDim.x + threadIdx.x;
  int e = gid >> 5;              // 32 threads per edge
  if (e >= E) return;
  int c = gid & 31;              // float4 chunk 0..31
  int sv = src[e];
  int dv = dst[e];
  float4 v = *reinterpret_cast<const float4*>(hv + (size_t)sv * 128 + c * 4);
  float* sp = s + (size_t)dv * 128 + c * 4;
  atomicAdd(sp + 0, v.x);
  atomicAdd(sp + 1, v.y);
  atomicAdd(sp + 2, v.z);
  atomicAdd(sp + 3, v.w);
  if (c == 0) {
    atomicAdd(g + dv, he[e]);
    atomicAdd(deg + dv, 1.0f);
  }
}

// G[M,512] = x[M,384] @ Wbig[512,384]^T, x on-the-fly from (deg*hv | s | hv)
__global__ __launch_bounds__(256) void gemm_kernel(
    const float* __restrict__ hv, const float* __restrict__ s,
    const float* __restrict__ deg, const float* __restrict__ Wbig,
    float* __restrict__ G, int M) {
  __shared__ float As[BK][LDSD];
  __shared__ float Bs[BK][LDSD];
  int m0 = blockIdx.x * BM;
  int n0 = blockIdx.y * BN;
  int tid = threadIdx.x;
  int tx = tid & 15, ty = tid >> 4;
  int lm = tid >> 2;             // 0..63
  int lk = (tid & 3) * 4;        // 0,4,8,12
  int vA = m0 + lm;
  bool mv = vA < M;
  float dv = mv ? deg[vA] : 0.0f;
  float acc[4][4] = {};
  for (int k0 = 0; k0 < 384; k0 += BK) {
    float4 av = make_float4(0.f, 0.f, 0.f, 0.f);
    if (mv) {
      if (k0 < 128) {
        av = *reinterpret_cast<const float4*>(hv + (size_t)vA * 128 + k0 + lk);
        av.x *= dv; av.y *= dv; av.z *= dv; av.w *= dv;
      } else if (k0 < 256) {
        av = *reinterpret_cast<const float4*>(s + (size_t)vA * 128 + (k0 - 128) + lk);
      } else {
        av = *reinterpret_cast<const float4*>(hv + (size_t)vA * 128 + (k0 - 256) + lk);
      }
    }
    As[lk + 0][lm] = av.x; As[lk + 1][lm] = av.y;
    As[lk + 2][lm] = av.z; As[lk + 3][lm] = av.w;
    const float* wr = Wbig + (size_t)(n0 + lm) * 384 + k0 + lk;
    float4 bv = *reinterpret_cast<const float4*>(wr);
    Bs[lk + 0][lm] = bv.x; Bs[lk + 1][lm] = bv.y;
    Bs[lk + 2][lm] = bv.z; Bs[lk + 3][lm] = bv.w;
    __syncthreads();
#pragma unroll
    for (int kk = 0; kk < BK; ++kk) {
      float a0 = As[kk][ty * 4 + 0], a1 = As[kk][ty * 4 + 1];
      float a2 = As[kk][ty * 4 + 2], a3 = As[kk][ty * 4 + 3];
      float b0 = Bs[kk][tx * 4 + 0], b1 = Bs[kk][tx * 4 + 1];
      float b2 = Bs[kk][tx * 4 + 2], b3 = Bs[kk][tx * 4 + 3];
      acc[0][0] += a0 * b0; acc[0][1] += a0 * b1; acc[0][2] += a0 * b2; acc[0][3] += a0 * b3;
      acc[1][0] += a1 * b0; acc[1][1] += a1 * b1; acc[1][2] += a1 * b2; acc[1][3] += a1 * b3;
      acc[2][0] += a2 * b0; acc[2][1] += a2 * b1; acc[2][2] += a2 * b2; acc[2][3] += a2 * b3;
      acc[3][0] += a3 * b0; acc[3][1] += a3 * b1; acc[3][2] += a3 * b2; acc[3][3] += a3 * b3;
    }
    __syncthreads();
  }
#pragma unroll
  for (int i = 0; i < 4; ++i) {
    int r = m0 + ty * 4 + i;
    if (r >= M) continue;
#pragma unroll
    for (int j = 0; j < 4; ++j) {
      int o = n0 + tx * 4 + j;
      G[(size_t)r * 512 + o] = acc[i][j];
    }
  }
}

// PyTorch GRUCell gates (r,z,n):
//  pre_r = G[:,j]     + deg*c1[j]     + g*c2[j]     + bih[j]     + bhh[j]
//  pre_z = G[:,128+j] + deg*c1[128+j] + g*c2[128+j] + bih[128+j] + bhh[128+j]
//  i_n   = G[:,256+j] + deg*c1[256+j] + g*c2[256+j] + bih[256+j]
//  h_n   = G[:,384+j] + bhh[256+j]
//  h' = (1-z)*tanh(i_n + r*h_n) + z*h
__global__ void gru_gate_kernel(const float* __restrict__ G,
                                const float* __restrict__ degv,
                                const float* __restrict__ gv,
                                const float* __restrict__ cvec,
                                const float* __restrict__ bih,
                                const float* __restrict__ bhh,
                                const float* __restrict__ hv_in,
                                float* __restrict__ hv_out, int Nn) {
  int gid = blockIdx.x * blockDim.x + threadIdx.x;
  int v = gid >> 7;
  if (v >= Nn) return;
  int j = gid & 127;
  float d = degv[v], gg = gv[v];
  const float* Gr = G + (size_t)v * 512;
  float pre_r = Gr[j]       + d * cvec[j]       + gg * cvec[384 + j]       + bih[j]       + bhh[j];
  float pre_z = Gr[128 + j] + d * cvec[128 + j] + gg * cvec[384 + 128 + j] + bih[128 + j] + bhh[128 + j];
  float i_n   = Gr[256 + j] + d * cvec[256 + j] + gg * cvec[384 + 256 + j] + bih[256 + j];
  float h_n   = Gr[384 + j] + bhh[256 + j];
  float r = 1.0f / (1.0f + expf(-pre_r));
  float z = 1.0f / (1.0f + expf(-pre_z));
  float n = tanhf(i_n + r * h_n);
  float h = hv_in[(size_t)v * 128 + j];
  hv_out[(size_t)v * 128 + j] = (1.0f - z) * n + z * h;
}

extern "C" void kernel_launch(void* const* d_in, const int* in_sizes, int n_in,
                              void* d_out, int out_size, void* d_ws, size_t ws_size,
                              hipStream_t stream) {
  const float* hv0  = (const float*)d_in[0];
  const float* he   = (const float*)d_in[1];
  const int*   src  = (const int*)d_in[2];
  const int*   dst  = (const int*)d_in[3];
  const float* Wmsg = (const float*)d_in[4];
  const float* bmsg = (const float*)d_in[5];
  const float* Wih  = (const float*)d_in[6];
  const float* Whh  = (const float*)d_in[7];
  const float* bih  = (const float*)d_in[8];
  const float* bhh  = (const float*)d_in[9];

  int N = in_sizes[0] / 128;
  int E = in_sizes[1];
  int T = in_sizes[4] / (256 * 257);

  // ws (floats): s[N*128] | g[N] | deg[N] | G[N*512] | Wbig[T*512*384] | cvec[T*768]
  size_t need = ((size_t)N * 642 + (size_t)T * (512 * 384 + 768)) * sizeof(float);
  if (ws_size < need) return;  // clean absmax failure instead of OOB crash

  float* ws   = (float*)d_ws;
  float* s    = ws;
  float* g    = ws + (size_t)N * 128;
  float* deg  = ws + (size_t)N * 129;
  float* G    = ws + (size_t)N * 130;
  float* Wbig = ws + (size_t)N * 642;
  float* cvec = Wbig + (size_t)T * 512 * 384;
  float* out  = (float*)d_out;

  {
    dim3 gb((386 + 63) / 64, 512, T);
    build_wbig_kernel<<<gb, 64, 0, stream>>>(Wih, Whh, Wmsg, bmsg, Wbig, cvec);
  }

  for (int t = 0; t < T; ++t) {
    const float* hv_in = (t == 0) ? hv0 : out;
    hipMemsetAsync(s, 0, (size_t)N * 130 * sizeof(float), stream);  // s, g, deg
    long long nthr = (long long)E * 32;
    edge_scatter_kernel<<<(int)((nthr + 255) / 256), 256, 0, stream>>>(
        hv_in, he, src, dst, s, g, deg, E);
    dim3 g1((N + BM - 1) / BM, 512 / BN);
    gemm_kernel<<<g1, 256, 0, stream>>>(
        hv_in, s, deg, Wbig + (size_t)t * 512 * 384, G, N);
    gru_gate_kernel<<<((size_t)N * 128 + 255) / 256, 256, 0, stream>>>(
        G, deg, g, cvec + (size_t)t * 768, bih + (size_t)t * 384, bhh + (size_t)t * 384,
        hv_in, out, N);
  }
}

// Round 4
// 972.929 us; speedup vs baseline: 3.6415x; 3.6415x over previous
//
#include <hip/hip_runtime.h>

// GraphProp: N nodes, E edges, H=128, T rounds.
// Identity 1 (linearity of segment_sum over the edge GEMM):
//   a[v] = deg(v)*(Wd@hv[v] + bmsg) + Ws@s[v] + g[v]*we
//   with s[v]=sum hv[src_e], g[v]=sum he_e over incoming edges of v.
// Identity 2 (per-row scalar deg commutes with the GRU input GEMM):
//   gi = Wih@a + bih = A1@(deg*hv) + A2@s + deg*c1 + g*c2 + bih.
// One GEMM per round: G[v] = Wbig @ x[v], x=[deg*hv | s | hv] (384),
//   Wbig rows 0:256 = r,z (gi+gh); 256:384 = i_n A-part; 384:512 = h_n.
// Round-4 change: s via CSR gather (build once per call), NOT fp32 atomics —
// scatter was 80% of runtime with 1.69 GB/dispatch HBM writes (atomics are
// device-scope, uncacheable in per-XCD L2 -> write amplification).

#define BM 64
#define BN 64
#define BK 16
#define LDSD 68   // 68 floats = 272B stride, 16B-aligned for b128 LDS reads

__global__ void build_wbig_kernel(const float* __restrict__ Wih,
                                  const float* __restrict__ Whh,
                                  const float* __restrict__ Wmsg,
                                  const float* __restrict__ bmsg,
                                  float* __restrict__ Wbig,
                                  float* __restrict__ cvec) {
  int c = blockIdx.x * blockDim.x + threadIdx.x;  // 0..385 (384=c1, 385=c2)
  int o = blockIdx.y;                             // 0..511
  int t = blockIdx.z;
  if (c >= 386) return;
  const float* wih  = Wih  + (size_t)t * 384 * 256;
  const float* whh  = Whh  + (size_t)t * 384 * 128;
  const float* wmsg = Wmsg + (size_t)t * 256 * 257;
  const float* bm   = bmsg + (size_t)t * 256;
  float* wb = Wbig + (size_t)t * 512 * 384;
  float* cv = cvec + (size_t)t * 768;
  if (c < 384) {
    float val = 0.0f;
    if (c < 256) {
      if (o < 384) {                 // A1|A2 = Wih @ Wmsg[:, 0:256]
        float acc = 0.0f;
        for (int k = 0; k < 256; ++k) acc += wih[(size_t)o * 256 + k] * wmsg[(size_t)k * 257 + c];
        val = acc;
      }
    } else {
      if (o < 256)       val = whh[(size_t)o * 128 + (c - 256)];
      else if (o >= 384) val = whh[(size_t)(256 + o - 384) * 128 + (c - 256)];
    }
    wb[(size_t)o * 384 + c] = val;
  } else if (o < 384) {
    float acc = 0.0f;
    if (c == 384) {
      for (int k = 0; k < 256; ++k) acc += wih[(size_t)o * 256 + k] * bm[k];
      cv[o] = acc;                   // c1
    } else {
      for (int k = 0; k < 256; ++k) acc += wih[(size_t)o * 256 + k] * wmsg[(size_t)k * 257 + 256];
      cv[384 + o] = acc;             // c2
    }
  }
}

// ---- CSR build (once per call; depends only on src/dst/he) ----

__global__ void csr_count_kernel(const int* __restrict__ dst,
                                 const float* __restrict__ he,
                                 int* __restrict__ counts,
                                 float* __restrict__ g, int E) {
  int e = blockIdx.x * blockDim.x + threadIdx.x;
  if (e >= E) return;
  int d = dst[e];
  atomicAdd(&counts[d], 1);
  atomicAdd(&g[d], he[e]);
}

// Single-block exclusive scan of counts[N] -> row_start[N+1] and cursor copy.
// 1024 threads = 16 waves; shfl wave-scan + LDS wave-offset scan (2 syncs/chunk).
__global__ __launch_bounds__(1024) void scan_kernel(const int* __restrict__ counts,
                                                    int* __restrict__ row_start,
                                                    int* __restrict__ cursor,
                                                    int N, int E) {
  __shared__ int wtot[16];
  __shared__ int woff[16];
  __shared__ int carry_s;
  int tid = threadIdx.x;
  int lane = tid & 63, w = tid >> 6;
  if (tid == 0) carry_s = 0;
  __syncthreads();
  for (int base = 0; base < N; base += 1024) {
    int i = base + tid;
    int x = (i < N) ? counts[i] : 0;
    int incl = x;
#pragma unroll
    for (int off = 1; off < 64; off <<= 1) {
      int y = __shfl_up(incl, off);
      if (lane >= off) incl += y;
    }
    if (lane == 63) wtot[w] = incl;
    __syncthreads();
    int carry = carry_s;
    if (w == 0 && lane < 16) {
      int wv = wtot[lane];
      int wincl = wv;
#pragma unroll
      for (int off = 1; off < 16; off <<= 1) {
        int y = __shfl_up(wincl, off);
        if (lane >= off) wincl += y;
      }
      woff[lane] = wincl - wv;           // exclusive wave offset
      if (lane == 15) wtot[15] = wincl;  // chunk total (wtot[15] dead now)
    }
    __syncthreads();
    int excl = incl - x + woff[w] + carry;
    if (i < N) { row_start[i] = excl; cursor[i] = excl; }
    __syncthreads();
    if (tid == 0) carry_s = carry + wtot[15];
    __syncthreads();
  }
  if (tid == 0) row_start[N] = E;
}

__global__ void csr_bucket_kernel(const int* __restrict__ src,
                                  const int* __restrict__ dst,
                                  int* __restrict__ cursor,
                                  int* __restrict__ srcs_sorted, int E) {
  int e = blockIdx.x * blockDim.x + threadIdx.x;
  if (e >= E) return;
  int pos = atomicAdd(&cursor[dst[e]], 1);
  srcs_sorted[pos] = src[e];
}

// ---- per-round gather: s[v] = sum hv[src] over CSR row; deg from row diff ----
// One wave per node; lane owns 2 features (float2, 512B/row coalesced).
__global__ __launch_bounds__(256) void gather_kernel(const float* __restrict__ hv,
                                                     const int* __restrict__ row_start,
                                                     const int* __restrict__ srcs_sorted,
                                                     float* __restrict__ s,
                                                     float* __restrict__ deg, int N) {
  int w = threadIdx.x >> 6;
  int lane = threadIdx.x & 63;
  int v = blockIdx.x * 4 + w;
  if (v >= N) return;
  int r0 = row_start[v];
  int r1 = row_start[v + 1];
  float2 acc = make_float2(0.f, 0.f);
  for (int base = r0; base < r1; base += 64) {
    int nn = min(64, r1 - base);
    int myv = (lane < nn) ? srcs_sorted[base + lane] : 0;
#pragma unroll 4
    for (int j = 0; j < nn; ++j) {
      int sv = __shfl(myv, j);
      float2 h = *reinterpret_cast<const float2*>(hv + (size_t)sv * 128 + lane * 2);
      acc.x += h.x; acc.y += h.y;
    }
  }
  *reinterpret_cast<float2*>(s + (size_t)v * 128 + lane * 2) = acc;
  if (lane == 0) deg[v] = (float)(r1 - r0);
}

// G[M,512] = x[M,384] @ Wbig[512,384]^T, x on-the-fly from (deg*hv | s | hv)
__global__ __launch_bounds__(256) void gemm_kernel(
    const float* __restrict__ hv, const float* __restrict__ s,
    const float* __restrict__ deg, const float* __restrict__ Wbig,
    float* __restrict__ G, int M) {
  __shared__ float As[BK][LDSD];
  __shared__ float Bs[BK][LDSD];
  int m0 = blockIdx.x * BM;
  int n0 = blockIdx.y * BN;
  int tid = threadIdx.x;
  int tx = tid & 15, ty = tid >> 4;
  int lm = tid >> 2;             // 0..63
  int lk = (tid & 3) * 4;        // 0,4,8,12
  int vA = m0 + lm;
  bool mv = vA < M;
  float dv = mv ? deg[vA] : 0.0f;
  float acc[4][4] = {};
  for (int k0 = 0; k0 < 384; k0 += BK) {
    float4 av = make_float4(0.f, 0.f, 0.f, 0.f);
    if (mv) {
      if (k0 < 128) {
        av = *reinterpret_cast<const float4*>(hv + (size_t)vA * 128 + k0 + lk);
        av.x *= dv; av.y *= dv; av.z *= dv; av.w *= dv;
      } else if (k0 < 256) {
        av = *reinterpret_cast<const float4*>(s + (size_t)vA * 128 + (k0 - 128) + lk);
      } else {
        av = *reinterpret_cast<const float4*>(hv + (size_t)vA * 128 + (k0 - 256) + lk);
      }
    }
    As[lk + 0][lm] = av.x; As[lk + 1][lm] = av.y;
    As[lk + 2][lm] = av.z; As[lk + 3][lm] = av.w;
    const float* wr = Wbig + (size_t)(n0 + lm) * 384 + k0 + lk;
    float4 bv = *reinterpret_cast<const float4*>(wr);
    Bs[lk + 0][lm] = bv.x; Bs[lk + 1][lm] = bv.y;
    Bs[lk + 2][lm] = bv.z; Bs[lk + 3][lm] = bv.w;
    __syncthreads();
#pragma unroll
    for (int kk = 0; kk < BK; ++kk) {
      float a0 = As[kk][ty * 4 + 0], a1 = As[kk][ty * 4 + 1];
      float a2 = As[kk][ty * 4 + 2], a3 = As[kk][ty * 4 + 3];
      float b0 = Bs[kk][tx * 4 + 0], b1 = Bs[kk][tx * 4 + 1];
      float b2 = Bs[kk][tx * 4 + 2], b3 = Bs[kk][tx * 4 + 3];
      acc[0][0] += a0 * b0; acc[0][1] += a0 * b1; acc[0][2] += a0 * b2; acc[0][3] += a0 * b3;
      acc[1][0] += a1 * b0; acc[1][1] += a1 * b1; acc[1][2] += a1 * b2; acc[1][3] += a1 * b3;
      acc[2][0] += a2 * b0; acc[2][1] += a2 * b1; acc[2][2] += a2 * b2; acc[2][3] += a2 * b3;
      acc[3][0] += a3 * b0; acc[3][1] += a3 * b1; acc[3][2] += a3 * b2; acc[3][3] += a3 * b3;
    }
    __syncthreads();
  }
#pragma unroll
  for (int i = 0; i < 4; ++i) {
    int r = m0 + ty * 4 + i;
    if (r >= M) continue;
#pragma unroll
    for (int j = 0; j < 4; ++j) {
      int o = n0 + tx * 4 + j;
      G[(size_t)r * 512 + o] = acc[i][j];
    }
  }
}

// PyTorch GRUCell gates (r,z,n) with folded affine terms.
__global__ void gru_gate_kernel(const float* __restrict__ G,
                                const float* __restrict__ degv,
                                const float* __restrict__ gv,
                                const float* __restrict__ cvec,
                                const float* __restrict__ bih,
                                const float* __restrict__ bhh,
                                const float* __restrict__ hv_in,
                                float* __restrict__ hv_out, int Nn) {
  int gid = blockIdx.x * blockDim.x + threadIdx.x;
  int v = gid >> 7;
  if (v >= Nn) return;
  int j = gid & 127;
  float d = degv[v], gg = gv[v];
  const float* Gr = G + (size_t)v * 512;
  float pre_r = Gr[j]       + d * cvec[j]       + gg * cvec[384 + j]       + bih[j]       + bhh[j];
  float pre_z = Gr[128 + j] + d * cvec[128 + j] + gg * cvec[384 + 128 + j] + bih[128 + j] + bhh[128 + j];
  float i_n   = Gr[256 + j] + d * cvec[256 + j] + gg * cvec[384 + 256 + j] + bih[256 + j];
  float h_n   = Gr[384 + j] + bhh[256 + j];
  float r = 1.0f / (1.0f + expf(-pre_r));
  float z = 1.0f / (1.0f + expf(-pre_z));
  float n = tanhf(i_n + r * h_n);
  float h = hv_in[(size_t)v * 128 + j];
  hv_out[(size_t)v * 128 + j] = (1.0f - z) * n + z * h;
}

extern "C" void kernel_launch(void* const* d_in, const int* in_sizes, int n_in,
                              void* d_out, int out_size, void* d_ws, size_t ws_size,
                              hipStream_t stream) {
  const float* hv0  = (const float*)d_in[0];
  const float* he   = (const float*)d_in[1];
  const int*   src  = (const int*)d_in[2];
  const int*   dst  = (const int*)d_in[3];
  const float* Wmsg = (const float*)d_in[4];
  const float* bmsg = (const float*)d_in[5];
  const float* Wih  = (const float*)d_in[6];
  const float* Whh  = (const float*)d_in[7];
  const float* bih  = (const float*)d_in[8];
  const float* bhh  = (const float*)d_in[9];

  int N = in_sizes[0] / 128;
  int E = in_sizes[1];
  int T = in_sizes[4] / (256 * 257);

  // ws (floats): s[N*128] | g[N] | deg[N] | G[N*512] | Wbig[T*512*384] |
  //              cvec[T*768] | row_start[N+1] (int) | srcs_sorted[E] (int)
  // cursor/counts (int[N]) aliases G (G written later each round).
  size_t need = ((size_t)N * 642 + (size_t)T * (512 * 384 + 768) + (size_t)(N + 1 + E))
                * sizeof(float);
  if (ws_size < need) return;  // clean absmax failure instead of OOB crash

  float* ws   = (float*)d_ws;
  float* s    = ws;
  float* g    = ws + (size_t)N * 128;
  float* deg  = ws + (size_t)N * 129;
  float* G    = ws + (size_t)N * 130;
  float* Wbig = ws + (size_t)N * 642;
  float* cvec = Wbig + (size_t)T * 512 * 384;
  int* row_start   = (int*)(cvec + (size_t)T * 768);
  int* srcs_sorted = row_start + (N + 1);
  int* cursor      = (int*)G;            // scratch during CSR build only
  float* out  = (float*)d_out;

  {
    dim3 gb((386 + 63) / 64, 512, T);
    build_wbig_kernel<<<gb, 64, 0, stream>>>(Wih, Whh, Wmsg, bmsg, Wbig, cvec);
  }

  // CSR build, once per call
  hipMemsetAsync(cursor, 0, (size_t)N * sizeof(int), stream);
  hipMemsetAsync(g, 0, (size_t)N * sizeof(float), stream);
  csr_count_kernel<<<(E + 255) / 256, 256, 0, stream>>>(dst, he, cursor, g, E);
  scan_kernel<<<1, 1024, 0, stream>>>(cursor, row_start, cursor, N, E);
  csr_bucket_kernel<<<(E + 255) / 256, 256, 0, stream>>>(src, dst, cursor, srcs_sorted, E);

  for (int t = 0; t < T; ++t) {
    const float* hv_in = (t == 0) ? hv0 : out;
    gather_kernel<<<(N + 3) / 4, 256, 0, stream>>>(hv_in, row_start, srcs_sorted, s, deg, N);
    dim3 g1((N + BM - 1) / BM, 512 / BN);
    gemm_kernel<<<g1, 256, 0, stream>>>(
        hv_in, s, deg, Wbig + (size_t)t * 512 * 384, G, N);
    gru_gate_kernel<<<((size_t)N * 128 + 255) / 256, 256, 0, stream>>>(
        G, deg, g, cvec + (size_t)t * 768, bih + (size_t)t * 384, bhh + (size_t)t * 384,
        hv_in, out, N);
  }
}

// Round 7
// 672.112 us; speedup vs baseline: 5.2713x; 1.4476x over previous
//
#include <hip/hip_runtime.h>

// GraphProp: N nodes, E edges, H=128, T rounds.
// a[v] = deg(v)*(Wd@hv+bmsg) + Ws@s[v] + g[v]*we  (linearity of segment_sum)
// gi = Wih@a folds into Wbig so ONE GEMM per round: G[v] = Wbig @ x[v],
//   x = [deg*hv | s | hv] (384), Wbig [512x384]:
//   rows 0:128=r(gi+gh), 128:256=z(gi+gh), 256:384=i_n A-part, 384:512=h_n.
// Round-7: fp16 (NOT bf16 — bf16's 8-bit mantissa gave absmax 0.39 vs thr
// 0.096; fp16's 11 bits is ~16x tighter, est. absmax ~0.03). GEMM via
// mfma_f32_16x16x32_f16 with the GRU gate fused in the epilogue: wave
// computes 4 gate PLANES (cols j,128+j,256+j,384+j) of one 16-row tile ->
// gate math is lane-local (C layout col=lane&15, row=(lane>>4)*4+reg).

using f16x8 = __attribute__((ext_vector_type(8))) _Float16;
using f32x4 = __attribute__((ext_vector_type(4))) float;

struct h2 { _Float16 x, y; };
struct h4 { _Float16 a, b, c, d; };

// ---- Wbig build (once per call): fp16 weights + fp32 cvec ----
__global__ void build_wbig_kernel(const float* __restrict__ Wih,
                                  const float* __restrict__ Whh,
                                  const float* __restrict__ Wmsg,
                                  const float* __restrict__ bmsg,
                                  _Float16* __restrict__ Wbig,
                                  float* __restrict__ cvec) {
  int c = blockIdx.x * blockDim.x + threadIdx.x;  // 0..385 (384=c1, 385=c2)
  int o = blockIdx.y;                             // 0..511
  int t = blockIdx.z;
  if (c >= 386) return;
  const float* wih  = Wih  + (size_t)t * 384 * 256;
  const float* whh  = Whh  + (size_t)t * 384 * 128;
  const float* wmsg = Wmsg + (size_t)t * 256 * 257;
  const float* bm   = bmsg + (size_t)t * 256;
  _Float16* wb = Wbig + (size_t)t * 512 * 384;
  float* cv = cvec + (size_t)t * 768;
  if (c < 384) {
    float val = 0.0f;
    if (c < 256) {
      if (o < 384) {                 // A1|A2 = Wih @ Wmsg[:, 0:256]
        float acc = 0.0f;
        for (int k = 0; k < 256; ++k) acc += wih[(size_t)o * 256 + k] * wmsg[(size_t)k * 257 + c];
        val = acc;
      }
    } else {
      if (o < 256)       val = whh[(size_t)o * 128 + (c - 256)];
      else if (o >= 384) val = whh[(size_t)(256 + o - 384) * 128 + (c - 256)];
    }
    wb[(size_t)o * 384 + c] = (_Float16)val;
  } else if (o < 384) {
    float acc = 0.0f;
    if (c == 384) {
      for (int k = 0; k < 256; ++k) acc += wih[(size_t)o * 256 + k] * bm[k];
      cv[o] = acc;                   // c1
    } else {
      for (int k = 0; k < 256; ++k) acc += wih[(size_t)o * 256 + k] * wmsg[(size_t)k * 257 + 256];
      cv[384 + o] = acc;             // c2
    }
  }
}

// ---- CSR build (once per call) ----
__global__ void csr_count_kernel(const int* __restrict__ dst,
                                 const float* __restrict__ he,
                                 int* __restrict__ counts,
                                 float* __restrict__ g, int E) {
  int e = blockIdx.x * blockDim.x + threadIdx.x;
  if (e >= E) return;
  int d = dst[e];
  atomicAdd(&counts[d], 1);
  atomicAdd(&g[d], he[e]);
}

__global__ __launch_bounds__(1024) void scan_kernel(const int* __restrict__ counts,
                                                    int* __restrict__ row_start,
                                                    int* __restrict__ cursor,
                                                    int N, int E) {
  __shared__ int wtot[16];
  __shared__ int woff[16];
  __shared__ int carry_s;
  int tid = threadIdx.x;
  int lane = tid & 63, w = tid >> 6;
  if (tid == 0) carry_s = 0;
  __syncthreads();
  for (int base = 0; base < N; base += 1024) {
    int i = base + tid;
    int x = (i < N) ? counts[i] : 0;
    int incl = x;
#pragma unroll
    for (int off = 1; off < 64; off <<= 1) {
      int y = __shfl_up(incl, off);
      if (lane >= off) incl += y;
    }
    if (lane == 63) wtot[w] = incl;
    __syncthreads();
    int carry = carry_s;
    if (w == 0 && lane < 16) {
      int wv = wtot[lane];
      int wincl = wv;
#pragma unroll
      for (int off = 1; off < 16; off <<= 1) {
        int y = __shfl_up(wincl, off);
        if (lane >= off) wincl += y;
      }
      woff[lane] = wincl - wv;
      if (lane == 15) wtot[15] = wincl;
    }
    __syncthreads();
    int excl = incl - x + woff[w] + carry;
    if (i < N) { row_start[i] = excl; cursor[i] = excl; }
    __syncthreads();
    if (tid == 0) carry_s = carry + wtot[15];
    __syncthreads();
  }
  if (tid == 0) row_start[N] = E;
}

__global__ void csr_bucket_kernel(const int* __restrict__ src,
                                  const int* __restrict__ dst,
                                  int* __restrict__ cursor,
                                  int* __restrict__ srcs_sorted, int E) {
  int e = blockIdx.x * blockDim.x + threadIdx.x;
  if (e >= E) return;
  int pos = atomicAdd(&cursor[dst[e]], 1);
  srcs_sorted[pos] = src[e];
}

// ---- per round: hv fp32 -> hb fp16 ----
__global__ void convert_kernel(const float* __restrict__ hv,
                               _Float16* __restrict__ hb, int total4) {
  int i = blockIdx.x * blockDim.x + threadIdx.x;
  if (i >= total4) return;
  float4 v = *reinterpret_cast<const float4*>(hv + (size_t)i * 4);
  h4 o;
  o.a = (_Float16)v.x; o.b = (_Float16)v.y; o.c = (_Float16)v.z; o.d = (_Float16)v.w;
  *reinterpret_cast<h4*>(hb + (size_t)i * 4) = o;
}

// ---- per round: gather s[v]=sum hb[src], write xb=[deg*h | s | h] fp16 ----
// One wave per node; lane owns 2 features (4B loads, 256B/row coalesced).
__global__ __launch_bounds__(256) void prep_kernel(const _Float16* __restrict__ hb,
                                                   const int* __restrict__ row_start,
                                                   const int* __restrict__ srcs_sorted,
                                                   _Float16* __restrict__ xb,
                                                   float* __restrict__ deg, int N) {
  int w = threadIdx.x >> 6;
  int lane = threadIdx.x & 63;
  int v = blockIdx.x * 4 + w;
  if (v >= N) return;
  int r0 = row_start[v];
  int r1 = row_start[v + 1];
  float ax = 0.f, ay = 0.f;
  for (int base = r0; base < r1; base += 64) {
    int nn = min(64, r1 - base);
    int myv = (lane < nn) ? srcs_sorted[base + lane] : 0;
#pragma unroll 4
    for (int j = 0; j < nn; ++j) {
      int sv = __shfl(myv, j);
      h2 u = *reinterpret_cast<const h2*>(hb + (size_t)sv * 128 + lane * 2);
      ax += (float)u.x; ay += (float)u.y;
    }
  }
  float d = (float)(r1 - r0);
  h2 hu = *reinterpret_cast<const h2*>(hb + (size_t)v * 128 + lane * 2);
  _Float16* xr = xb + (size_t)v * 384;
  h2 dh; dh.x = (_Float16)(d * (float)hu.x); dh.y = (_Float16)(d * (float)hu.y);
  h2 ss; ss.x = (_Float16)ax; ss.y = (_Float16)ay;
  *reinterpret_cast<h2*>(xr + lane * 2)       = dh;
  *reinterpret_cast<h2*>(xr + 128 + lane * 2) = ss;
  *reinterpret_cast<h2*>(xr + 256 + lane * 2) = hu;
  if (lane == 0) deg[v] = d;
}

// ---- fused GEMM (fp16 MFMA) + GRU gate epilogue ----
// Block = 32 rows x all 512 cols. 4 waves split j: wave w -> j in [w*32,w*32+32).
// Per wave: 2 m-tiles x 2 j-tiles x 4 planes of 16x16x32 MFMA over K=384.
__global__ __launch_bounds__(256) void fused_gemm_gate_kernel(
    const _Float16* __restrict__ xb,
    const _Float16* __restrict__ wbig,
    const float* __restrict__ deg, const float* __restrict__ gv,
    const float* __restrict__ cvec,
    const float* __restrict__ bih, const float* __restrict__ bhh,
    const float* __restrict__ hv_in, float* __restrict__ hv_out, int M) {
  int wave = threadIdx.x >> 6;
  int lane = threadIdx.x & 63;
  int m0 = blockIdx.x * 32;
  int j0 = wave * 32;
  int lr = lane & 15;        // row within A tile / col within B tile
  int lk = (lane >> 4) * 8;  // k offset of the 8-elem fragment

  f32x4 acc[2][2][4];
#pragma unroll
  for (int m = 0; m < 2; ++m)
#pragma unroll
    for (int j = 0; j < 2; ++j)
#pragma unroll
      for (int p = 0; p < 4; ++p) acc[m][j][p] = (f32x4){0.f, 0.f, 0.f, 0.f};

  int ar0 = m0 + lr;                   // A row, m-tile 0
  int ar1 = min(m0 + 16 + lr, M - 1);  // clamped (stores guarded below)
  const _Float16* xp0 = xb + (size_t)ar0 * 384 + lk;
  const _Float16* xp1 = xb + (size_t)ar1 * 384 + lk;

  for (int k0 = 0; k0 < 384; k0 += 32) {
    f16x8 a0 = *reinterpret_cast<const f16x8*>(xp0 + k0);
    f16x8 a1 = *reinterpret_cast<const f16x8*>(xp1 + k0);
#pragma unroll
    for (int p = 0; p < 4; ++p) {
#pragma unroll
      for (int j = 0; j < 2; ++j) {
        int col = p * 128 + j0 + j * 16 + lr;
        f16x8 b = *reinterpret_cast<const f16x8*>(wbig + (size_t)col * 384 + k0 + lk);
        acc[0][j][p] = __builtin_amdgcn_mfma_f32_16x16x32_f16(a0, b, acc[0][j][p], 0, 0, 0);
        acc[1][j][p] = __builtin_amdgcn_mfma_f32_16x16x32_f16(a1, b, acc[1][j][p], 0, 0, 0);
      }
    }
  }

  // epilogue: C layout col=lane&15, row=(lane>>4)*4+reg (m89-verified, dtype-indep)
#pragma unroll
  for (int m = 0; m < 2; ++m) {
#pragma unroll
    for (int reg = 0; reg < 4; ++reg) {
      int v = m0 + m * 16 + (lane >> 4) * 4 + reg;
      if (v >= M) continue;
      float d = deg[v], gg = gv[v];
#pragma unroll
      for (int j = 0; j < 2; ++j) {
        int jj = j0 + j * 16 + lr;          // 0..127
        float Gr = acc[m][j][0][reg];
        float Gz = acc[m][j][1][reg];
        float Gn = acc[m][j][2][reg];
        float Gh = acc[m][j][3][reg];
        float pre_r = Gr + d * cvec[jj]       + gg * cvec[384 + jj]       + bih[jj]       + bhh[jj];
        float pre_z = Gz + d * cvec[128 + jj] + gg * cvec[384 + 128 + jj] + bih[128 + jj] + bhh[128 + jj];
        float i_n   = Gn + d * cvec[256 + jj] + gg * cvec[384 + 256 + jj] + bih[256 + jj];
        float h_n   = Gh + bhh[256 + jj];
        float r = 1.0f / (1.0f + expf(-pre_r));
        float z = 1.0f / (1.0f + expf(-pre_z));
        float n = tanhf(i_n + r * h_n);
        float h = hv_in[(size_t)v * 128 + jj];
        hv_out[(size_t)v * 128 + jj] = (1.0f - z) * n + z * h;
      }
    }
  }
}

extern "C" void kernel_launch(void* const* d_in, const int* in_sizes, int n_in,
                              void* d_out, int out_size, void* d_ws, size_t ws_size,
                              hipStream_t stream) {
  const float* hv0  = (const float*)d_in[0];
  const float* he   = (const float*)d_in[1];
  const int*   src  = (const int*)d_in[2];
  const int*   dst  = (const int*)d_in[3];
  const float* Wmsg = (const float*)d_in[4];
  const float* bmsg = (const float*)d_in[5];
  const float* Wih  = (const float*)d_in[6];
  const float* Whh  = (const float*)d_in[7];
  const float* bih  = (const float*)d_in[8];
  const float* bhh  = (const float*)d_in[9];

  int N = in_sizes[0] / 128;
  int E = in_sizes[1];
  int T = in_sizes[4] / (256 * 257);

  // ws bytes: hb f16[N*128] | xb f16[N*384] | deg f32[N] | g f32[N] |
  //           cvec f32[T*768] | wbig f16[T*512*384] | row_start int[N+1] |
  //           srcs_sorted int[E].   cursor aliases xb (CSR build precedes prep).
  size_t off = 0;
  auto alloc = [&](size_t bytes) { size_t o = off; off += (bytes + 15) & ~(size_t)15; return o; };
  size_t o_hb   = alloc((size_t)N * 128 * 2);
  size_t o_xb   = alloc((size_t)N * 384 * 2);
  size_t o_deg  = alloc((size_t)N * 4);
  size_t o_g    = alloc((size_t)N * 4);
  size_t o_cv   = alloc((size_t)T * 768 * 4);
  size_t o_wb   = alloc((size_t)T * 512 * 384 * 2);
  size_t o_rs   = alloc((size_t)(N + 1) * 4);
  size_t o_ss   = alloc((size_t)E * 4);
  if (ws_size < off) return;  // clean failure instead of OOB crash

  char* wsb = (char*)d_ws;
  _Float16* hb     = (_Float16*)(wsb + o_hb);
  _Float16* xb     = (_Float16*)(wsb + o_xb);
  float* deg       = (float*)(wsb + o_deg);
  float* g         = (float*)(wsb + o_g);
  float* cvec      = (float*)(wsb + o_cv);
  _Float16* wbig   = (_Float16*)(wsb + o_wb);
  int* row_start   = (int*)(wsb + o_rs);
  int* srcs_sorted = (int*)(wsb + o_ss);
  int* cursor      = (int*)xb;  // scratch during CSR build only
  float* out = (float*)d_out;

  {
    dim3 gb((386 + 63) / 64, 512, T);
    build_wbig_kernel<<<gb, 64, 0, stream>>>(Wih, Whh, Wmsg, bmsg, wbig, cvec);
  }

  hipMemsetAsync(cursor, 0, (size_t)N * sizeof(int), stream);
  hipMemsetAsync(g, 0, (size_t)N * sizeof(float), stream);
  csr_count_kernel<<<(E + 255) / 256, 256, 0, stream>>>(dst, he, cursor, g, E);
  scan_kernel<<<1, 1024, 0, stream>>>(cursor, row_start, cursor, N, E);
  csr_bucket_kernel<<<(E + 255) / 256, 256, 0, stream>>>(src, dst, cursor, srcs_sorted, E);

  for (int t = 0; t < T; ++t) {
    const float* hv_in = (t == 0) ? hv0 : out;
    int total4 = N * 128 / 4;
    convert_kernel<<<(total4 + 255) / 256, 256, 0, stream>>>(hv_in, hb, total4);
    prep_kernel<<<(N + 3) / 4, 256, 0, stream>>>(hb, row_start, srcs_sorted, xb, deg, N);
    fused_gemm_gate_kernel<<<(N + 31) / 32, 256, 0, stream>>>(
        xb, wbig + (size_t)t * 512 * 384, deg, g, cvec + (size_t)t * 768,
        bih + (size_t)t * 384, bhh + (size_t)t * 384, hv_in, out, N);
  }
}

// Round 8
// 522.745 us; speedup vs baseline: 6.7775x; 1.2857x over previous
//
#include <hip/hip_runtime.h>

// GraphProp: N nodes, E edges, H=128, T rounds.
// a[v] = deg(v)*(Wd@hv+bmsg) + Ws@s[v] + g[v]*we  (linearity of segment_sum)
// gi = Wih@a folds into Wbig: ONE GEMM per round G[v] = Wbig @ x[v],
//   x = [deg*hv | s | hv] (384), Wbig [512x384]:
//   rows 0:128=r(gi+gh), 128:256=z(gi+gh), 256:384=i_n A-part, 384:512=h_n.
// fp16 everywhere (bf16 failed absmax: 0.39 > 0.096; fp16 gives 0.052).
// Round-8: FRAGMENT-INTERLEAVED operand layouts. Round-7 profile showed the
// fused MFMA kernel latency-bound (MfmaUtil 5.6%, VALU 15%, HBM 5.5%): each
// fragment load touched 16 scattered 64B lines (stride-768B across 16 lanes),
// ~7cyc/line in the L1/TA pipe. Now WbigF[k0c][w][p][j][lane][8] and
// xbF[mtile][k0c][lane][8] make every load base+lane*16 = one contiguous
// 1KB burst. Same math, bit-identical output.

using f16x8 = __attribute__((ext_vector_type(8))) _Float16;
using f32x4 = __attribute__((ext_vector_type(4))) float;

struct h2 { _Float16 x, y; };
struct h4 { _Float16 a, b, c, d; };

// ---- Wbig build (once per call): fp16 weights (interleaved) + fp32 cvec ----
// WbigF element for (col o, k): p=o>>7, w=(o>>5)&3, j=(o>>4)&1, lr=o&15;
// k0c=k>>5, lkg=(k>>3)&3, kin=k&7;
// idx = (((k0c*4 + w)*4 + p)*2 + j)*512 + (lkg*16 + lr)*8 + kin
__global__ void build_wbig_kernel(const float* __restrict__ Wih,
                                  const float* __restrict__ Whh,
                                  const float* __restrict__ Wmsg,
                                  const float* __restrict__ bmsg,
                                  _Float16* __restrict__ WbigF,
                                  float* __restrict__ cvec) {
  int c = blockIdx.x * blockDim.x + threadIdx.x;  // 0..385 (384=c1, 385=c2)
  int o = blockIdx.y;                             // 0..511
  int t = blockIdx.z;
  if (c >= 386) return;
  const float* wih  = Wih  + (size_t)t * 384 * 256;
  const float* whh  = Whh  + (size_t)t * 384 * 128;
  const float* wmsg = Wmsg + (size_t)t * 256 * 257;
  const float* bm   = bmsg + (size_t)t * 256;
  _Float16* wb = WbigF + (size_t)t * 512 * 384;
  float* cv = cvec + (size_t)t * 768;
  if (c < 384) {
    float val = 0.0f;
    if (c < 256) {
      if (o < 384) {                 // A1|A2 = Wih @ Wmsg[:, 0:256]
        float acc = 0.0f;
        for (int k = 0; k < 256; ++k) acc += wih[(size_t)o * 256 + k] * wmsg[(size_t)k * 257 + c];
        val = acc;
      }
    } else {
      if (o < 256)       val = whh[(size_t)o * 128 + (c - 256)];
      else if (o >= 384) val = whh[(size_t)(256 + o - 384) * 128 + (c - 256)];
    }
    int p = o >> 7, w = (o >> 5) & 3, j = (o >> 4) & 1, lr = o & 15;
    int k0c = c >> 5, lkg = (c >> 3) & 3, kin = c & 7;
    size_t idx = (size_t)((((k0c * 4 + w) * 4 + p) * 2 + j)) * 512 + (lkg * 16 + lr) * 8 + kin;
    wb[idx] = (_Float16)val;
  } else if (o < 384) {
    float acc = 0.0f;
    if (c == 384) {
      for (int k = 0; k < 256; ++k) acc += wih[(size_t)o * 256 + k] * bm[k];
      cv[o] = acc;                   // c1
    } else {
      for (int k = 0; k < 256; ++k) acc += wih[(size_t)o * 256 + k] * wmsg[(size_t)k * 257 + 256];
      cv[384 + o] = acc;             // c2
    }
  }
}

// ---- CSR build (once per call) ----
__global__ void csr_count_kernel(const int* __restrict__ dst,
                                 const float* __restrict__ he,
                                 int* __restrict__ counts,
                                 float* __restrict__ g, int E) {
  int e = blockIdx.x * blockDim.x + threadIdx.x;
  if (e >= E) return;
  int d = dst[e];
  atomicAdd(&counts[d], 1);
  atomicAdd(&g[d], he[e]);
}

__global__ __launch_bounds__(1024) void scan_kernel(const int* __restrict__ counts,
                                                    int* __restrict__ row_start,
                                                    int* __restrict__ cursor,
                                                    int N, int E) {
  __shared__ int wtot[16];
  __shared__ int woff[16];
  __shared__ int carry_s;
  int tid = threadIdx.x;
  int lane = tid & 63, w = tid >> 6;
  if (tid == 0) carry_s = 0;
  __syncthreads();
  for (int base = 0; base < N; base += 1024) {
    int i = base + tid;
    int x = (i < N) ? counts[i] : 0;
    int incl = x;
#pragma unroll
    for (int off = 1; off < 64; off <<= 1) {
      int y = __shfl_up(incl, off);
      if (lane >= off) incl += y;
    }
    if (lane == 63) wtot[w] = incl;
    __syncthreads();
    int carry = carry_s;
    if (w == 0 && lane < 16) {
      int wv = wtot[lane];
      int wincl = wv;
#pragma unroll
      for (int off = 1; off < 16; off <<= 1) {
        int y = __shfl_up(wincl, off);
        if (lane >= off) wincl += y;
      }
      woff[lane] = wincl - wv;
      if (lane == 15) wtot[15] = wincl;
    }
    __syncthreads();
    int excl = incl - x + woff[w] + carry;
    if (i < N) { row_start[i] = excl; cursor[i] = excl; }
    __syncthreads();
    if (tid == 0) carry_s = carry + wtot[15];
    __syncthreads();
  }
  if (tid == 0) row_start[N] = E;
}

__global__ void csr_bucket_kernel(const int* __restrict__ src,
                                  const int* __restrict__ dst,
                                  int* __restrict__ cursor,
                                  int* __restrict__ srcs_sorted, int E) {
  int e = blockIdx.x * blockDim.x + threadIdx.x;
  if (e >= E) return;
  int pos = atomicAdd(&cursor[dst[e]], 1);
  srcs_sorted[pos] = src[e];
}

// ---- per round: hv fp32 -> hb fp16 ----
__global__ void convert_kernel(const float* __restrict__ hv,
                               _Float16* __restrict__ hb, int total4) {
  int i = blockIdx.x * blockDim.x + threadIdx.x;
  if (i >= total4) return;
  float4 v = *reinterpret_cast<const float4*>(hv + (size_t)i * 4);
  h4 o;
  o.a = (_Float16)v.x; o.b = (_Float16)v.y; o.c = (_Float16)v.z; o.d = (_Float16)v.w;
  *reinterpret_cast<h4*>(hb + (size_t)i * 4) = o;
}

// ---- per round: gather s[v]=sum hb[src]; write xbF fragment-interleaved ----
// One wave per node; lane owns x-cols {2*lane, 2*lane+1} of each 128-plane.
// Explicit 4-deep edge batching for load ILP (runtime-bound loops don't unroll).
__global__ __launch_bounds__(256) void prep_kernel(const _Float16* __restrict__ hb,
                                                   const int* __restrict__ row_start,
                                                   const int* __restrict__ srcs_sorted,
                                                   _Float16* __restrict__ xbF,
                                                   float* __restrict__ deg, int N) {
  int w = threadIdx.x >> 6;
  int lane = threadIdx.x & 63;
  int v = blockIdx.x * 4 + w;
  if (v >= N) return;
  int r0 = row_start[v];
  int r1 = row_start[v + 1];
  float ax = 0.f, ay = 0.f;
  for (int base = r0; base < r1; base += 64) {
    int nn = min(64, r1 - base);
    int myv = (lane < nn) ? srcs_sorted[base + lane] : 0;
    int j = 0;
    for (; j + 4 <= nn; j += 4) {
      int s0 = __shfl(myv, j + 0), s1 = __shfl(myv, j + 1);
      int s2 = __shfl(myv, j + 2), s3 = __shfl(myv, j + 3);
      h2 u0 = *reinterpret_cast<const h2*>(hb + (size_t)s0 * 128 + lane * 2);
      h2 u1 = *reinterpret_cast<const h2*>(hb + (size_t)s1 * 128 + lane * 2);
      h2 u2 = *reinterpret_cast<const h2*>(hb + (size_t)s2 * 128 + lane * 2);
      h2 u3 = *reinterpret_cast<const h2*>(hb + (size_t)s3 * 128 + lane * 2);
      ax += (float)u0.x + (float)u1.x + (float)u2.x + (float)u3.x;
      ay += (float)u0.y + (float)u1.y + (float)u2.y + (float)u3.y;
    }
    for (; j < nn; ++j) {
      int sv = __shfl(myv, j);
      h2 u = *reinterpret_cast<const h2*>(hb + (size_t)sv * 128 + lane * 2);
      ax += (float)u.x; ay += (float)u.y;
    }
  }
  float d = (float)(r1 - r0);
  h2 hu = *reinterpret_cast<const h2*>(hb + (size_t)v * 128 + lane * 2);
  h2 dh; dh.x = (_Float16)(d * (float)hu.x); dh.y = (_Float16)(d * (float)hu.y);
  h2 ss; ss.x = (_Float16)ax; ss.y = (_Float16)ay;
  int mt = v >> 4, lrv = v & 15;
  _Float16* xmt = xbF + (size_t)mt * 12 * 512;
  auto store2 = [&](int c, h2 val) {
    int k0c = c >> 5, lkg = (c >> 3) & 3, kin = c & 7;
    _Float16* p = xmt + (size_t)k0c * 512 + (lkg * 16 + lrv) * 8 + kin;
    *reinterpret_cast<h2*>(p) = val;
  };
  store2(lane * 2, dh);            // plane 0: deg*h   (x-cols 0..127)
  store2(128 + lane * 2, ss);      // plane 1: s       (x-cols 128..255)
  store2(256 + lane * 2, hu);      // plane 2: h       (x-cols 256..383)
  if (lane == 0) deg[v] = d;
}

// ---- fused GEMM (fp16 MFMA) + GRU gate epilogue ----
// Block = 32 rows x 512 cols, 4 waves; wave w covers cols p*128+w*32+j*16+lr.
// All fragment loads are base+lane*16 contiguous 1KB bursts (L2-resident).
__global__ __launch_bounds__(256) void fused_gemm_gate_kernel(
    const _Float16* __restrict__ xbF,
    const _Float16* __restrict__ wbigF,
    const float* __restrict__ deg, const float* __restrict__ gv,
    const float* __restrict__ cvec,
    const float* __restrict__ bih, const float* __restrict__ bhh,
    const float* __restrict__ hv_in, float* __restrict__ hv_out, int M) {
  int wave = threadIdx.x >> 6;
  int lane = threadIdx.x & 63;
  int m0 = blockIdx.x * 32;
  int Mt = (M + 15) >> 4;
  int mt0 = m0 >> 4;
  int mt1 = min(mt0 + 1, Mt - 1);

  f32x4 acc[2][2][4];  // [m][j][p]
#pragma unroll
  for (int m = 0; m < 2; ++m)
#pragma unroll
    for (int j = 0; j < 2; ++j)
#pragma unroll
      for (int p = 0; p < 4; ++p) acc[m][j][p] = (f32x4){0.f, 0.f, 0.f, 0.f};

  const _Float16* a0p = xbF + (size_t)mt0 * 12 * 512 + lane * 8;
  const _Float16* a1p = xbF + (size_t)mt1 * 12 * 512 + lane * 8;
  // B elem: (((k0c*4 + w)*4 + p)*2 + j)*512 + lane*8
  const _Float16* bp = wbigF + (size_t)wave * 4096 + lane * 8;

  for (int k0c = 0; k0c < 12; ++k0c) {
    f16x8 a0 = *reinterpret_cast<const f16x8*>(a0p + (size_t)k0c * 512);
    f16x8 a1 = *reinterpret_cast<const f16x8*>(a1p + (size_t)k0c * 512);
    const _Float16* bk = bp + (size_t)k0c * 16384;
#pragma unroll
    for (int p = 0; p < 4; ++p) {
#pragma unroll
      for (int j = 0; j < 2; ++j) {
        f16x8 b = *reinterpret_cast<const f16x8*>(bk + (p * 2 + j) * 512);
        acc[0][j][p] = __builtin_amdgcn_mfma_f32_16x16x32_f16(a0, b, acc[0][j][p], 0, 0, 0);
        acc[1][j][p] = __builtin_amdgcn_mfma_f32_16x16x32_f16(a1, b, acc[1][j][p], 0, 0, 0);
      }
    }
  }

  // epilogue: C layout col=lane&15, row=(lane>>4)*4+reg (m89-verified)
  int lr = lane & 15;
  int j0 = wave * 32;
#pragma unroll
  for (int m = 0; m < 2; ++m) {
#pragma unroll
    for (int reg = 0; reg < 4; ++reg) {
      int v = m0 + m * 16 + (lane >> 4) * 4 + reg;
      if (v >= M) continue;
      float d = deg[v], gg = gv[v];
#pragma unroll
      for (int j = 0; j < 2; ++j) {
        int jj = j0 + j * 16 + lr;          // 0..127
        float Gr = acc[m][j][0][reg];
        float Gz = acc[m][j][1][reg];
        float Gn = acc[m][j][2][reg];
        float Gh = acc[m][j][3][reg];
        float pre_r = Gr + d * cvec[jj]       + gg * cvec[384 + jj]       + bih[jj]       + bhh[jj];
        float pre_z = Gz + d * cvec[128 + jj] + gg * cvec[384 + 128 + jj] + bih[128 + jj] + bhh[128 + jj];
        float i_n   = Gn + d * cvec[256 + jj] + gg * cvec[384 + 256 + jj] + bih[256 + jj];
        float h_n   = Gh + bhh[256 + jj];
        float r = 1.0f / (1.0f + expf(-pre_r));
        float z = 1.0f / (1.0f + expf(-pre_z));
        float n = tanhf(i_n + r * h_n);
        float h = hv_in[(size_t)v * 128 + jj];
        hv_out[(size_t)v * 128 + jj] = (1.0f - z) * n + z * h;
      }
    }
  }
}

extern "C" void kernel_launch(void* const* d_in, const int* in_sizes, int n_in,
                              void* d_out, int out_size, void* d_ws, size_t ws_size,
                              hipStream_t stream) {
  const float* hv0  = (const float*)d_in[0];
  const float* he   = (const float*)d_in[1];
  const int*   src  = (const int*)d_in[2];
  const int*   dst  = (const int*)d_in[3];
  const float* Wmsg = (const float*)d_in[4];
  const float* bmsg = (const float*)d_in[5];
  const float* Wih  = (const float*)d_in[6];
  const float* Whh  = (const float*)d_in[7];
  const float* bih  = (const float*)d_in[8];
  const float* bhh  = (const float*)d_in[9];

  int N = in_sizes[0] / 128;
  int E = in_sizes[1];
  int T = in_sizes[4] / (256 * 257);
  int Mt = (N + 15) / 16;

  size_t off = 0;
  auto alloc = [&](size_t bytes) { size_t o = off; off += (bytes + 15) & ~(size_t)15; return o; };
  size_t o_hb   = alloc((size_t)N * 128 * 2);
  size_t o_xb   = alloc((size_t)Mt * 12 * 512 * 2);
  size_t o_deg  = alloc((size_t)N * 4);
  size_t o_g    = alloc((size_t)N * 4);
  size_t o_cv   = alloc((size_t)T * 768 * 4);
  size_t o_wb   = alloc((size_t)T * 512 * 384 * 2);
  size_t o_rs   = alloc((size_t)(N + 1) * 4);
  size_t o_ss   = alloc((size_t)E * 4);
  if (ws_size < off) return;  // clean failure instead of OOB crash

  char* wsb = (char*)d_ws;
  _Float16* hb     = (_Float16*)(wsb + o_hb);
  _Float16* xbF    = (_Float16*)(wsb + o_xb);
  float* deg       = (float*)(wsb + o_deg);
  float* g         = (float*)(wsb + o_g);
  float* cvec      = (float*)(wsb + o_cv);
  _Float16* wbigF  = (_Float16*)(wsb + o_wb);
  int* row_start   = (int*)(wsb + o_rs);
  int* srcs_sorted = (int*)(wsb + o_ss);
  int* cursor      = (int*)xbF;  // scratch during CSR build only
  float* out = (float*)d_out;

  {
    dim3 gb((386 + 63) / 64, 512, T);
    build_wbig_kernel<<<gb, 64, 0, stream>>>(Wih, Whh, Wmsg, bmsg, wbigF, cvec);
  }

  hipMemsetAsync(cursor, 0, (size_t)N * sizeof(int), stream);
  hipMemsetAsync(g, 0, (size_t)N * sizeof(float), stream);
  csr_count_kernel<<<(E + 255) / 256, 256, 0, stream>>>(dst, he, cursor, g, E);
  scan_kernel<<<1, 1024, 0, stream>>>(cursor, row_start, cursor, N, E);
  csr_bucket_kernel<<<(E + 255) / 256, 256, 0, stream>>>(src, dst, cursor, srcs_sorted, E);

  for (int t = 0; t < T; ++t) {
    const float* hv_in = (t == 0) ? hv0 : out;
    int total4 = N * 128 / 4;
    convert_kernel<<<(total4 + 255) / 256, 256, 0, stream>>>(hv_in, hb, total4);
    prep_kernel<<<(N + 3) / 4, 256, 0, stream>>>(hb, row_start, srcs_sorted, xbF, deg, N);
    fused_gemm_gate_kernel<<<(N + 31) / 32, 256, 0, stream>>>(
        xbF, wbigF + (size_t)t * 512 * 384, deg, g, cvec + (size_t)t * 768,
        bih + (size_t)t * 384, bhh + (size_t)t * 384, hv_in, out, N);
  }
}